// Round 2
// baseline (18917.569 us; speedup 1.0000x reference)
//
#include <hip/hip_runtime.h>
#include <hip/hip_bf16.h>
#include <cstdint>

#define S_LEN 512
#define BATCH 64
#define IDIM  1024
#define HDIM  1024
#define G4    4096
#define NBLK  256   // recurrence grid

typedef __attribute__((ext_vector_type(8))) short short8;
typedef __attribute__((ext_vector_type(4))) float f32x4;
typedef __attribute__((ext_vector_type(4))) unsigned short ushort4v;
typedef __attribute__((ext_vector_type(4))) unsigned int uint4v;

__device__ __forceinline__ unsigned short f2bf(float f){
  union { float f; unsigned u; } v; v.f = f;
  unsigned r = (v.u + 0x7fffu + ((v.u >> 16) & 1u)) >> 16;
  return (unsigned short)r;
}
__device__ __forceinline__ float bf2f(unsigned short s){
  union { unsigned u; float f; } v; v.u = ((unsigned)s) << 16;
  return v.f;
}
__device__ __forceinline__ float sigf(float x){ return 1.0f / (1.0f + __expf(-x)); }
__device__ __forceinline__ float tanhf_fast(float x){
  float e = __expf(2.0f * x);
  return 1.0f - 2.0f / (e + 1.0f);
}
__device__ __forceinline__ f32x4 mfma_bf16(short8 a, short8 b, f32x4 c){
  return __builtin_amdgcn_mfma_f32_16x16x32_bf16(a, b, c, 0, 0, 0);
}

// xg packed-load/store helpers (f32 or bf16 storage)
__device__ __forceinline__ f32x4 xg_load(const float* p){ return *reinterpret_cast<const f32x4*>(p); }
__device__ __forceinline__ f32x4 xg_load(const unsigned short* p){
  ushort4v u = *reinterpret_cast<const ushort4v*>(p);
  f32x4 r; r[0]=bf2f(u[0]); r[1]=bf2f(u[1]); r[2]=bf2f(u[2]); r[3]=bf2f(u[3]);
  return r;
}
__device__ __forceinline__ void xg_store(float* p, f32x4 v){ *reinterpret_cast<f32x4*>(p) = v; }
__device__ __forceinline__ void xg_store(unsigned short* p, f32x4 v){
  ushort4v u; u[0]=f2bf(v[0]); u[1]=f2bf(v[1]); u[2]=f2bf(v[2]); u[3]=f2bf(v[3]);
  *reinterpret_cast<ushort4v*>(p) = u;
}

// ---------------------------------------------------------------------------
// prep: pack W_hh into per-block MFMA-B-fragment order (bf16), bias sum, h0->bf16
// ---------------------------------------------------------------------------
__global__ __launch_bounds__(256) void prep_kernel(
    const float* __restrict__ Whh, const float* __restrict__ bih,
    const float* __restrict__ bhh, const float* __restrict__ h0,
    unsigned short* __restrict__ Wpack, float* __restrict__ biasSum,
    unsigned short* __restrict__ hA){
  int i = blockIdx.x * 256 + threadIdx.x;
  if (i < G4) biasSum[i] = bih[i] + bhh[i];
  if (i < BATCH*HDIM) hA[i] = f2bf(h0[i]);
  if (i < G4*HDIM){
    int e = i & 7, l = (i >> 3) & 63, ks = (i >> 9) & 31, bk = i >> 14;
    int c = l & 15, q = l >> 4;
    int row = (c >> 2) * HDIM + bk * 4 + (c & 3);
    int k = ks * 32 + q * 8 + e;
    Wpack[i] = f2bf(Whh[row * HDIM + k]);
  }
}

// ---------------------------------------------------------------------------
// x_gates GEMM: out[m][n] = sum_k In[m][k] * Wih[n][k] + biasSum[n]
// Writes packed xg[s][bk][c][b].
// ---------------------------------------------------------------------------
template<typename XGT>
__global__ __launch_bounds__(256) void xg_gemm(
    const float* __restrict__ In, const float* __restrict__ Wih,
    const float* __restrict__ biasSum, XGT* __restrict__ xg){
  __shared__ __align__(16) unsigned short Abuf[128 * 72];
  __shared__ __align__(16) unsigned short Bbuf[128 * 72];
  const int bid = blockIdx.x;
  const int tm = bid >> 5, tn = bid & 31;
  const int bm0 = tm * 128, bn0 = tn * 128;
  const int tid = threadIdx.x;
  const int wid = tid >> 6, l = tid & 63;
  const int wm = wid >> 1, wn = wid & 1;
  const int lr = tid >> 4;
  const int lk = (tid & 15) * 4;

  f32x4 acc[4][4];
  #pragma unroll
  for (int a = 0; a < 4; ++a)
    #pragma unroll
    for (int b = 0; b < 4; ++b) acc[a][b] = (f32x4){0.f, 0.f, 0.f, 0.f};

  for (int kt = 0; kt < 16; ++kt){
    #pragma unroll
    for (int it = 0; it < 8; ++it){
      int r = lr + it * 16;
      f32x4 a4 = *reinterpret_cast<const f32x4*>(&In[(size_t)(bm0 + r) * IDIM + kt * 64 + lk]);
      ushort4v ab; ab[0]=f2bf(a4[0]); ab[1]=f2bf(a4[1]); ab[2]=f2bf(a4[2]); ab[3]=f2bf(a4[3]);
      *reinterpret_cast<ushort4v*>(&Abuf[r * 72 + lk]) = ab;
      f32x4 b4 = *reinterpret_cast<const f32x4*>(&Wih[(size_t)(bn0 + r) * IDIM + kt * 64 + lk]);
      ushort4v bb; bb[0]=f2bf(b4[0]); bb[1]=f2bf(b4[1]); bb[2]=f2bf(b4[2]); bb[3]=f2bf(b4[3]);
      *reinterpret_cast<ushort4v*>(&Bbuf[r * 72 + lk]) = bb;
    }
    __syncthreads();
    #pragma unroll
    for (int ks = 0; ks < 2; ++ks){
      short8 af[4], bfv[4];
      #pragma unroll
      for (int f = 0; f < 4; ++f){
        af[f]  = *reinterpret_cast<const short8*>(&Abuf[(wm*64 + f*16 + (l & 15)) * 72 + ks*32 + (l >> 4) * 8]);
        bfv[f] = *reinterpret_cast<const short8*>(&Bbuf[(wn*64 + f*16 + (l & 15)) * 72 + ks*32 + (l >> 4) * 8]);
      }
      #pragma unroll
      for (int fm = 0; fm < 4; ++fm)
        #pragma unroll
        for (int fn = 0; fn < 4; ++fn)
          acc[fm][fn] = mfma_bf16(af[fm], bfv[fn], acc[fm][fn]);
    }
    __syncthreads();
  }

  const int q = l >> 4, c16 = l & 15;
  #pragma unroll
  for (int fn = 0; fn < 4; ++fn){
    int n = bn0 + wn * 64 + fn * 16 + c16;
    float bias = biasSum[n];
    int bkk = (n & 1023) >> 2;
    int cc = ((n >> 10) << 2) | (n & 3);
    #pragma unroll
    for (int fm = 0; fm < 4; ++fm){
      int m0 = bm0 + wm * 64 + fm * 16 + q * 4;
      int s = m0 >> 6, b0 = m0 & 63;
      f32x4 v = acc[fm][fn];
      v[0] += bias; v[1] += bias; v[2] += bias; v[3] += bias;
      size_t base = (((size_t)s * 256 + bkk) * 16 + cc) * 64 + b0;
      xg_store(&xg[base], v);
    }
  }
}

// ---------------------------------------------------------------------------
// recurrence: 256 persistent blocks; flag-array grid barrier (no atomic RMW).
// Block bk owns h-cols jj = bk*4+{0..3} (16 W_hh rows in LDS).
// ---------------------------------------------------------------------------
template<typename XGT>
__global__ __launch_bounds__(256) void recur_kernel(
    const float* __restrict__ h0, const float* __restrict__ c0,
    const float* __restrict__ ret, const unsigned short* __restrict__ Wpack,
    const XGT* __restrict__ xg, unsigned short* __restrict__ hA,
    unsigned short* __restrict__ hB, float* __restrict__ out,
    float* __restrict__ hc_out, unsigned* __restrict__ flags){
  __shared__ __align__(16) unsigned short Wlds[16384];   // 32 KB: [ks][lane][8]
  __shared__ float gates[64 * 17];

  const int bk = blockIdx.x;
  const int tid = threadIdx.x;

  {
    const uint4v* src = reinterpret_cast<const uint4v*>(Wpack + (size_t)bk * 16384);
    uint4v* dst = reinterpret_cast<uint4v*>(Wlds);
    #pragma unroll
    for (int it = 0; it < 8; ++it) dst[it * 256 + tid] = src[it * 256 + tid];
  }

  const int b = tid >> 2, j = tid & 3, jj = bk * 4 + j;
  float c_reg = c0[b * HDIM + jj];
  float h_reg = h0[b * HDIM + jj];
  float r_reg = ret[jj];

  const int w = tid >> 6, l = tid & 63;
  const int arow = w * 16 + (l & 15);
  const int kq = (l >> 4) * 8;
  const int c16 = l & 15;
  const int b0 = w * 16 + (l >> 4) * 4;

  __syncthreads();

  for (int s = 0; s < S_LEN; ++s){
    const unsigned short* cur = (s & 1) ? hB : hA;
    unsigned short* nxt = (s & 1) ? hA : hB;

    f32x4 acc = (f32x4){0.f, 0.f, 0.f, 0.f};
    const unsigned short* ap = cur + (size_t)arow * HDIM + kq;
    #pragma unroll 8
    for (int ks = 0; ks < 32; ++ks){
      short8 a = *reinterpret_cast<const short8*>(ap + ks * 32);
      short8 bw = *reinterpret_cast<const short8*>(&Wlds[ks * 512 + l * 8]);
      acc = mfma_bf16(a, bw, acc);
    }
    {
      size_t xbase = (((size_t)s * 256 + bk) * 16 + c16) * 64 + b0;
      f32x4 xv = xg_load(&xg[xbase]);
      #pragma unroll
      for (int r = 0; r < 4; ++r)
        gates[(b0 + r) * 17 + c16] = acc[r] + xv[r];
    }
    __syncthreads();

    {
      float gi = gates[b * 17 + j];
      float gf = gates[b * 17 + 4 + j];
      float gg = gates[b * 17 + 8 + j];
      float go = gates[b * 17 + 12 + j];
      float ig = sigf(gi), fg = sigf(gf), gt = tanhf_fast(gg), og = sigf(go);
      float cy = fg * c_reg + ig * gt;
      float hy = og * tanhf_fast(cy);
      hy = r_reg * h_reg + (1.0f - r_reg) * hy;
      c_reg = cy; h_reg = hy;
      nxt[b * HDIM + jj] = f2bf(hy);
      out[((size_t)s * BATCH + b) * HDIM + jj] = hy;
    }

    // ---- flag-array grid barrier: arrive = 1 parallel store per block; ----
    // ---- wait = each thread polls one block's flag (no atomic RMWs).     ----
    __syncthreads();                 // all h stores issued
    if (tid == 0){
      __threadfence();               // write back dirty L2 (h visible device-wide)
      __hip_atomic_store(&flags[bk], (unsigned)(s + 1), __ATOMIC_RELEASE,
                         __HIP_MEMORY_SCOPE_AGENT);
    }
    {
      const unsigned tgt = (unsigned)(s + 1);
      unsigned spins = 0;
      while (__hip_atomic_load(&flags[tid], __ATOMIC_RELAXED,
                               __HIP_MEMORY_SCOPE_AGENT) < tgt){
        __builtin_amdgcn_s_sleep(2);
        if (++spins > 100000000u) break;   // safety bailout, never expected
      }
    }
    __syncthreads();                 // whole block saw all 256 flags
    __threadfence();                 // acquire: invalidate stale L1/L2 before reading h
  }

  hc_out[b * HDIM + jj] = h_reg;
  hc_out[BATCH * HDIM + b * HDIM + jj] = c_reg;
}

// ---------------------------------------------------------------------------
extern "C" void kernel_launch(void* const* d_in, const int* in_sizes, int n_in,
                              void* d_out, int out_size, void* d_ws, size_t ws_size,
                              hipStream_t stream){
  const float* In  = (const float*)d_in[0];
  const float* h0  = (const float*)d_in[1];
  const float* c0  = (const float*)d_in[2];
  const float* Wih = (const float*)d_in[3];
  const float* Whh = (const float*)d_in[4];
  const float* bih = (const float*)d_in[5];
  const float* bhh = (const float*)d_in[6];
  const float* ret = (const float*)d_in[7];
  float* out = (float*)d_out;

  char* ws = (char*)d_ws;
  const size_t off_flags = 0;                         // 1 KB (256 u32)
  const size_t off_bias  = 1024;                      // 16 KB
  const size_t off_hA    = 17408;
  const size_t off_hB    = off_hA + 131072;
  const size_t off_wp    = off_hB + 131072;
  const size_t off_xg    = off_wp + 8388608;
  const size_t xg_elems  = (size_t)S_LEN * G4 * BATCH;
  const size_t need_f32  = off_xg + xg_elems * 4;
  const size_t need_b16  = off_xg + xg_elems * 2;

  unsigned*       flags   = (unsigned*)(ws + off_flags);
  float*          biasSum = (float*)(ws + off_bias);
  unsigned short* hA      = (unsigned short*)(ws + off_hA);
  unsigned short* hB      = (unsigned short*)(ws + off_hB);
  unsigned short* Wpack   = (unsigned short*)(ws + off_wp);

  if (ws_size < need_b16) return;  // cannot run; fail validation loudly

  (void)hipMemsetAsync(ws + off_flags, 0, 1024, stream);
  prep_kernel<<<16384, 256, 0, stream>>>(Whh, bih, bhh, h0, Wpack, biasSum, hA);

  float* hc_out = out + (size_t)S_LEN * BATCH * HDIM;
  if (ws_size >= need_f32){
    float* xg = (float*)(ws + off_xg);
    xg_gemm<float><<<8192, 256, 0, stream>>>(In, Wih, biasSum, xg);
    recur_kernel<float><<<NBLK, 256, 0, stream>>>(h0, c0, ret, Wpack, xg, hA, hB,
                                                  out, hc_out, flags);
  } else {
    unsigned short* xg = (unsigned short*)(ws + off_xg);
    xg_gemm<unsigned short><<<8192, 256, 0, stream>>>(In, Wih, biasSum, xg);
    recur_kernel<unsigned short><<<NBLK, 256, 0, stream>>>(h0, c0, ret, Wpack, xg,
                                                           hA, hB, out, hc_out, flags);
  }
}

// Round 3
// 5438.915 us; speedup vs baseline: 3.4782x; 3.4782x over previous
//
#include <hip/hip_runtime.h>
#include <hip/hip_bf16.h>
#include <cstdint>

#define S_LEN 512
#define BATCH 64
#define IDIM  1024
#define HDIM  1024
#define G4    4096
#define NBLK  256   // recurrence grid

typedef __attribute__((ext_vector_type(8))) short short8;
typedef __attribute__((ext_vector_type(4))) float f32x4;
typedef __attribute__((ext_vector_type(4))) unsigned short ushort4v;
typedef __attribute__((ext_vector_type(4))) unsigned int uint4v;

__device__ __forceinline__ unsigned short f2bf(float f){
  union { float f; unsigned u; } v; v.f = f;
  unsigned r = (v.u + 0x7fffu + ((v.u >> 16) & 1u)) >> 16;
  return (unsigned short)r;
}
__device__ __forceinline__ float bf2f(unsigned short s){
  union { unsigned u; float f; } v; v.u = ((unsigned)s) << 16;
  return v.f;
}
__device__ __forceinline__ float sigf(float x){ return 1.0f / (1.0f + __expf(-x)); }
__device__ __forceinline__ float tanhf_fast(float x){
  float e = __expf(2.0f * x);
  return 1.0f - 2.0f / (e + 1.0f);
}
__device__ __forceinline__ f32x4 mfma_bf16(short8 a, short8 b, f32x4 c){
  return __builtin_amdgcn_mfma_f32_16x16x32_bf16(a, b, c, 0, 0, 0);
}

// ---- LLC-coherent (L1/L2-bypassing) accessors: the ONLY cross-block data ----
// 16 strided 16B loads (64B stride), waitcnt inside the block (self-contained,
// no split-issue/wait hazard). sc0 sc1 => read at LLC, never stale L2.
__device__ __forceinline__ void load16_bypass(const unsigned short* p, short8* d){
  asm volatile(
    "global_load_dwordx4 %0, %16, off sc0 sc1\n\t"
    "global_load_dwordx4 %1, %16, off offset:64 sc0 sc1\n\t"
    "global_load_dwordx4 %2, %16, off offset:128 sc0 sc1\n\t"
    "global_load_dwordx4 %3, %16, off offset:192 sc0 sc1\n\t"
    "global_load_dwordx4 %4, %16, off offset:256 sc0 sc1\n\t"
    "global_load_dwordx4 %5, %16, off offset:320 sc0 sc1\n\t"
    "global_load_dwordx4 %6, %16, off offset:384 sc0 sc1\n\t"
    "global_load_dwordx4 %7, %16, off offset:448 sc0 sc1\n\t"
    "global_load_dwordx4 %8, %16, off offset:512 sc0 sc1\n\t"
    "global_load_dwordx4 %9, %16, off offset:576 sc0 sc1\n\t"
    "global_load_dwordx4 %10, %16, off offset:640 sc0 sc1\n\t"
    "global_load_dwordx4 %11, %16, off offset:704 sc0 sc1\n\t"
    "global_load_dwordx4 %12, %16, off offset:768 sc0 sc1\n\t"
    "global_load_dwordx4 %13, %16, off offset:832 sc0 sc1\n\t"
    "global_load_dwordx4 %14, %16, off offset:896 sc0 sc1\n\t"
    "global_load_dwordx4 %15, %16, off offset:960 sc0 sc1\n\t"
    "s_waitcnt vmcnt(0)"
    : "=&v"(d[0]), "=&v"(d[1]), "=&v"(d[2]), "=&v"(d[3]),
      "=&v"(d[4]), "=&v"(d[5]), "=&v"(d[6]), "=&v"(d[7]),
      "=&v"(d[8]), "=&v"(d[9]), "=&v"(d[10]), "=&v"(d[11]),
      "=&v"(d[12]), "=&v"(d[13]), "=&v"(d[14]), "=&v"(d[15])
    : "v"(p)
    : "memory");
}
__device__ __forceinline__ void store_short_bypass(unsigned short* p, unsigned v){
  asm volatile("global_store_short %0, %1, off sc0 sc1" :: "v"(p), "v"(v) : "memory");
}
__device__ __forceinline__ void store_dword_bypass(unsigned* p, unsigned v){
  asm volatile("global_store_dword %0, %1, off sc0 sc1" :: "v"(p), "v"(v) : "memory");
}
__device__ __forceinline__ uint4v load4_flags_bypass(const unsigned* p){
  uint4v f;
  asm volatile("global_load_dwordx4 %0, %1, off sc0 sc1\n\ts_waitcnt vmcnt(0)"
               : "=&v"(f) : "v"(p) : "memory");
  return f;
}

// xg packed-load/store helpers (f32 or bf16 storage)
__device__ __forceinline__ f32x4 xg_load(const float* p){ return *reinterpret_cast<const f32x4*>(p); }
__device__ __forceinline__ f32x4 xg_load(const unsigned short* p){
  ushort4v u = *reinterpret_cast<const ushort4v*>(p);
  f32x4 r; r[0]=bf2f(u[0]); r[1]=bf2f(u[1]); r[2]=bf2f(u[2]); r[3]=bf2f(u[3]);
  return r;
}
__device__ __forceinline__ void xg_store(float* p, f32x4 v){ *reinterpret_cast<f32x4*>(p) = v; }
__device__ __forceinline__ void xg_store(unsigned short* p, f32x4 v){
  ushort4v u; u[0]=f2bf(v[0]); u[1]=f2bf(v[1]); u[2]=f2bf(v[2]); u[3]=f2bf(v[3]);
  *reinterpret_cast<ushort4v*>(p) = u;
}

// ---------------------------------------------------------------------------
// prep: pack W_hh into per-block MFMA-B-fragment order (bf16), bias sum, h0->bf16
// ---------------------------------------------------------------------------
__global__ __launch_bounds__(256) void prep_kernel(
    const float* __restrict__ Whh, const float* __restrict__ bih,
    const float* __restrict__ bhh, const float* __restrict__ h0,
    unsigned short* __restrict__ Wpack, float* __restrict__ biasSum,
    unsigned short* __restrict__ hA){
  int i = blockIdx.x * 256 + threadIdx.x;
  if (i < G4) biasSum[i] = bih[i] + bhh[i];
  if (i < BATCH*HDIM) hA[i] = f2bf(h0[i]);
  if (i < G4*HDIM){
    int e = i & 7, l = (i >> 3) & 63, ks = (i >> 9) & 31, bk = i >> 14;
    int c = l & 15, q = l >> 4;
    int row = (c >> 2) * HDIM + bk * 4 + (c & 3);
    int k = ks * 32 + q * 8 + e;
    Wpack[i] = f2bf(Whh[row * HDIM + k]);
  }
}

// ---------------------------------------------------------------------------
// x_gates GEMM: out[m][n] = sum_k In[m][k] * Wih[n][k] + biasSum[n]
// Writes packed xg[s][bk][c][b].
// ---------------------------------------------------------------------------
template<typename XGT>
__global__ __launch_bounds__(256) void xg_gemm(
    const float* __restrict__ In, const float* __restrict__ Wih,
    const float* __restrict__ biasSum, XGT* __restrict__ xg){
  __shared__ __align__(16) unsigned short Abuf[128 * 72];
  __shared__ __align__(16) unsigned short Bbuf[128 * 72];
  const int bid = blockIdx.x;
  const int tm = bid >> 5, tn = bid & 31;
  const int bm0 = tm * 128, bn0 = tn * 128;
  const int tid = threadIdx.x;
  const int wid = tid >> 6, l = tid & 63;
  const int wm = wid >> 1, wn = wid & 1;
  const int lr = tid >> 4;
  const int lk = (tid & 15) * 4;

  f32x4 acc[4][4];
  #pragma unroll
  for (int a = 0; a < 4; ++a)
    #pragma unroll
    for (int b = 0; b < 4; ++b) acc[a][b] = (f32x4){0.f, 0.f, 0.f, 0.f};

  for (int kt = 0; kt < 16; ++kt){
    #pragma unroll
    for (int it = 0; it < 8; ++it){
      int r = lr + it * 16;
      f32x4 a4 = *reinterpret_cast<const f32x4*>(&In[(size_t)(bm0 + r) * IDIM + kt * 64 + lk]);
      ushort4v ab; ab[0]=f2bf(a4[0]); ab[1]=f2bf(a4[1]); ab[2]=f2bf(a4[2]); ab[3]=f2bf(a4[3]);
      *reinterpret_cast<ushort4v*>(&Abuf[r * 72 + lk]) = ab;
      f32x4 b4 = *reinterpret_cast<const f32x4*>(&Wih[(size_t)(bn0 + r) * IDIM + kt * 64 + lk]);
      ushort4v bb; bb[0]=f2bf(b4[0]); bb[1]=f2bf(b4[1]); bb[2]=f2bf(b4[2]); bb[3]=f2bf(b4[3]);
      *reinterpret_cast<ushort4v*>(&Bbuf[r * 72 + lk]) = bb;
    }
    __syncthreads();
    #pragma unroll
    for (int ks = 0; ks < 2; ++ks){
      short8 af[4], bfv[4];
      #pragma unroll
      for (int f = 0; f < 4; ++f){
        af[f]  = *reinterpret_cast<const short8*>(&Abuf[(wm*64 + f*16 + (l & 15)) * 72 + ks*32 + (l >> 4) * 8]);
        bfv[f] = *reinterpret_cast<const short8*>(&Bbuf[(wn*64 + f*16 + (l & 15)) * 72 + ks*32 + (l >> 4) * 8]);
      }
      #pragma unroll
      for (int fm = 0; fm < 4; ++fm)
        #pragma unroll
        for (int fn = 0; fn < 4; ++fn)
          acc[fm][fn] = mfma_bf16(af[fm], bfv[fn], acc[fm][fn]);
    }
    __syncthreads();
  }

  const int q = l >> 4, c16 = l & 15;
  #pragma unroll
  for (int fn = 0; fn < 4; ++fn){
    int n = bn0 + wn * 64 + fn * 16 + c16;
    float bias = biasSum[n];
    int bkk = (n & 1023) >> 2;
    int cc = ((n >> 10) << 2) | (n & 3);
    #pragma unroll
    for (int fm = 0; fm < 4; ++fm){
      int m0 = bm0 + wm * 64 + fm * 16 + q * 4;
      int s = m0 >> 6, b0 = m0 & 63;
      f32x4 v = acc[fm][fn];
      v[0] += bias; v[1] += bias; v[2] += bias; v[3] += bias;
      size_t base = (((size_t)s * 256 + bkk) * 16 + cc) * 64 + b0;
      xg_store(&xg[base], v);
    }
  }
}

// ---------------------------------------------------------------------------
// recurrence: 256 persistent blocks; NO fences in the loop. Cross-block h and
// barrier flags go through LLC-coherent sc0/sc1 accesses; __syncthreads'
// vmcnt(0) drain provides release ordering.
// ---------------------------------------------------------------------------
template<typename XGT>
__global__ __launch_bounds__(256) void recur_kernel(
    const float* __restrict__ h0, const float* __restrict__ c0,
    const float* __restrict__ ret, const unsigned short* __restrict__ Wpack,
    const XGT* __restrict__ xg, unsigned short* __restrict__ hA,
    unsigned short* __restrict__ hB, float* __restrict__ out,
    float* __restrict__ hc_out, unsigned* __restrict__ flags){
  __shared__ __align__(16) unsigned short Wlds[16384];   // 32 KB: [ks][lane][8]
  __shared__ float gates[64 * 17];

  const int bk = blockIdx.x;
  const int tid = threadIdx.x;

  {
    const uint4v* src = reinterpret_cast<const uint4v*>(Wpack + (size_t)bk * 16384);
    uint4v* dst = reinterpret_cast<uint4v*>(Wlds);
    #pragma unroll
    for (int it = 0; it < 8; ++it) dst[it * 256 + tid] = src[it * 256 + tid];
  }

  const int b = tid >> 2, j = tid & 3, jj = bk * 4 + j;
  float c_reg = c0[b * HDIM + jj];
  float h_reg = h0[b * HDIM + jj];
  float r_reg = ret[jj];

  const int w = tid >> 6, l = tid & 63;
  const int arow = w * 16 + (l & 15);
  const int kq = (l >> 4) * 8;
  const int c16 = l & 15;
  const int b0 = w * 16 + (l >> 4) * 4;

  __syncthreads();

  for (int s = 0; s < S_LEN; ++s){
    const unsigned short* cur = (s & 1) ? hB : hA;
    unsigned short* nxt = (s & 1) ? hA : hB;

    // xg load first: independent of h, HBM latency hides under h-load+MFMA
    size_t xbase = (((size_t)s * 256 + bk) * 16 + c16) * 64 + b0;
    f32x4 xv = xg_load(&xg[xbase]);

    f32x4 acc = (f32x4){0.f, 0.f, 0.f, 0.f};
    const unsigned short* ap = cur + (size_t)arow * HDIM + kq;
    short8 hreg[16];
    #pragma unroll
    for (int half = 0; half < 2; ++half){
      load16_bypass(ap + half * 512, hreg);   // ks = half*16 .. +15 (64B stride)
      #pragma unroll
      for (int i = 0; i < 16; ++i){
        short8 bw = *reinterpret_cast<const short8*>(&Wlds[(half * 16 + i) * 512 + l * 8]);
        acc = mfma_bf16(hreg[i], bw, acc);
      }
    }
    #pragma unroll
    for (int r = 0; r < 4; ++r)
      gates[(b0 + r) * 17 + c16] = acc[r] + xv[r];
    __syncthreads();

    {
      float gi = gates[b * 17 + j];
      float gf = gates[b * 17 + 4 + j];
      float gg = gates[b * 17 + 8 + j];
      float go = gates[b * 17 + 12 + j];
      float ig = sigf(gi), fg = sigf(gf), gt = tanhf_fast(gg), og = sigf(go);
      float cy = fg * c_reg + ig * gt;
      float hy = og * tanhf_fast(cy);
      hy = r_reg * h_reg + (1.0f - r_reg) * hy;
      c_reg = cy; h_reg = hy;
      store_short_bypass(&nxt[b * HDIM + jj], (unsigned)f2bf(hy));  // LLC-visible
      out[((size_t)s * BATCH + b) * HDIM + jj] = hy;                // normal path
    }

    // ---- grid barrier: no fences, no RMWs ----
    __syncthreads();                       // vmcnt(0) drain: h stores at LLC
    const unsigned tgt = (unsigned)(s + 1);
    if (tid == 0)
      store_dword_bypass(&flags[bk], tgt); // arrival
    if (tid < 64){                         // wave 0: lane t checks flags[4t..4t+3]
      const unsigned* fp = flags + (tid << 2);
      unsigned spins = 0;
      for (;;){
        uint4v f = load4_flags_bypass(fp);
        if (f[0] >= tgt && f[1] >= tgt && f[2] >= tgt && f[3] >= tgt) break;
        if (++spins > 50000000u) break;    // safety bailout, never expected
      }
    }
    __syncthreads();                       // release all waves; h readable via bypass
  }

  hc_out[b * HDIM + jj] = h_reg;
  hc_out[BATCH * HDIM + b * HDIM + jj] = c_reg;
}

// ---------------------------------------------------------------------------
extern "C" void kernel_launch(void* const* d_in, const int* in_sizes, int n_in,
                              void* d_out, int out_size, void* d_ws, size_t ws_size,
                              hipStream_t stream){
  const float* In  = (const float*)d_in[0];
  const float* h0  = (const float*)d_in[1];
  const float* c0  = (const float*)d_in[2];
  const float* Wih = (const float*)d_in[3];
  const float* Whh = (const float*)d_in[4];
  const float* bih = (const float*)d_in[5];
  const float* bhh = (const float*)d_in[6];
  const float* ret = (const float*)d_in[7];
  float* out = (float*)d_out;

  char* ws = (char*)d_ws;
  const size_t off_flags = 0;                         // 1 KB (256 u32)
  const size_t off_bias  = 1024;
  const size_t off_hA    = 17408;
  const size_t off_hB    = off_hA + 131072;
  const size_t off_wp    = off_hB + 131072;
  const size_t off_xg    = off_wp + 8388608;
  const size_t xg_elems  = (size_t)S_LEN * G4 * BATCH;
  const size_t need_f32  = off_xg + xg_elems * 4;
  const size_t need_b16  = off_xg + xg_elems * 2;

  unsigned*       flags   = (unsigned*)(ws + off_flags);
  float*          biasSum = (float*)(ws + off_bias);
  unsigned short* hA      = (unsigned short*)(ws + off_hA);
  unsigned short* hB      = (unsigned short*)(ws + off_hB);
  unsigned short* Wpack   = (unsigned short*)(ws + off_wp);

  if (ws_size < need_b16) return;  // cannot run; fail validation loudly

  (void)hipMemsetAsync(ws + off_flags, 0, 1024, stream);
  prep_kernel<<<16384, 256, 0, stream>>>(Whh, bih, bhh, h0, Wpack, biasSum, hA);

  float* hc_out = out + (size_t)S_LEN * BATCH * HDIM;
  if (ws_size >= need_f32){
    float* xg = (float*)(ws + off_xg);
    xg_gemm<float><<<8192, 256, 0, stream>>>(In, Wih, biasSum, xg);
    recur_kernel<float><<<NBLK, 256, 0, stream>>>(h0, c0, ret, Wpack, xg, hA, hB,
                                                  out, hc_out, flags);
  } else {
    unsigned short* xg = (unsigned short*)(ws + off_xg);
    xg_gemm<unsigned short><<<8192, 256, 0, stream>>>(In, Wih, biasSum, xg);
    recur_kernel<unsigned short><<<NBLK, 256, 0, stream>>>(h0, c0, ret, Wpack, xg,
                                                           hA, hB, out, hc_out, flags);
  }
}

// Round 5
// 3788.420 us; speedup vs baseline: 4.9935x; 1.4357x over previous
//
#include <hip/hip_runtime.h>
#include <hip/hip_bf16.h>
#include <cstdint>

#define S_LEN 512
#define BATCH 64
#define IDIM  1024
#define HDIM  1024
#define G4    4096
#define NBLK  256   // recurrence grid: 4 batch-groups x 64 col-blocks

typedef __attribute__((ext_vector_type(8))) short short8;
typedef __attribute__((ext_vector_type(4))) float f32x4;
typedef __attribute__((ext_vector_type(4))) unsigned short ushort4v;
typedef __attribute__((ext_vector_type(4))) unsigned int uint4v;

__device__ __forceinline__ unsigned short f2bf(float f){
  union { float f; unsigned u; } v; v.f = f;
  unsigned r = (v.u + 0x7fffu + ((v.u >> 16) & 1u)) >> 16;
  return (unsigned short)r;
}
__device__ __forceinline__ float bf2f(unsigned short s){
  union { unsigned u; float f; } v; v.u = ((unsigned)s) << 16;
  return v.f;
}
__device__ __forceinline__ float sigf(float x){ return 1.0f / (1.0f + __expf(-x)); }
__device__ __forceinline__ float tanhf_fast(float x){
  float e = __expf(2.0f * x);
  return 1.0f - 2.0f / (e + 1.0f);
}
__device__ __forceinline__ f32x4 mfma_bf16(short8 a, short8 b, f32x4 c){
  return __builtin_amdgcn_mfma_f32_16x16x32_bf16(a, b, c, 0, 0, 0);
}
__device__ __forceinline__ float tofloat(float v){ return v; }
__device__ __forceinline__ float tofloat(unsigned short v){ return bf2f(v); }

// ---- LLC-coherent (L2-bypassing) helpers for cross-block data ----
// 8 strided 16B loads + INTERNAL vmcnt(0): self-contained, no cross-block
// vmcnt accounting (round-4 lesson: counted vmcnt across asm blocks retires
// in issue order — the youngest loads are the ones left in flight).
__device__ __forceinline__ void load8_bypass(const unsigned short* p, short8* d){
  asm volatile(
    "global_load_dwordx4 %0, %8, off sc0 sc1\n\t"
    "global_load_dwordx4 %1, %8, off offset:64 sc0 sc1\n\t"
    "global_load_dwordx4 %2, %8, off offset:128 sc0 sc1\n\t"
    "global_load_dwordx4 %3, %8, off offset:192 sc0 sc1\n\t"
    "global_load_dwordx4 %4, %8, off offset:256 sc0 sc1\n\t"
    "global_load_dwordx4 %5, %8, off offset:320 sc0 sc1\n\t"
    "global_load_dwordx4 %6, %8, off offset:384 sc0 sc1\n\t"
    "global_load_dwordx4 %7, %8, off offset:448 sc0 sc1\n\t"
    "s_waitcnt vmcnt(0)"
    : "=&v"(d[0]), "=&v"(d[1]), "=&v"(d[2]), "=&v"(d[3]),
      "=&v"(d[4]), "=&v"(d[5]), "=&v"(d[6]), "=&v"(d[7])
    : "v"(p)
    : "memory");
}
__device__ __forceinline__ void store_short_bypass(unsigned short* p, unsigned v){
  asm volatile("global_store_short %0, %1, off sc0 sc1" :: "v"(p), "v"(v) : "memory");
}
__device__ __forceinline__ void store_dword_bypass(unsigned* p, unsigned v){
  asm volatile("global_store_dword %0, %1, off sc0 sc1" :: "v"(p), "v"(v) : "memory");
}
__device__ __forceinline__ uint4v load4_flags_bypass(const unsigned* p){
  uint4v f;
  asm volatile("global_load_dwordx4 %0, %1, off sc0 sc1\n\ts_waitcnt vmcnt(0)"
               : "=&v"(f) : "v"(p) : "memory");
  return f;
}

// xg store helpers (f32 or bf16 storage)
__device__ __forceinline__ void xg_store(float* p, f32x4 v){ *reinterpret_cast<f32x4*>(p) = v; }
__device__ __forceinline__ void xg_store(unsigned short* p, f32x4 v){
  ushort4v u; u[0]=f2bf(v[0]); u[1]=f2bf(v[1]); u[2]=f2bf(v[2]); u[3]=f2bf(v[3]);
  *reinterpret_cast<ushort4v*>(p) = u;
}

// ---------------------------------------------------------------------------
// prep: pack W_hh into per-(cb,wave,gate,ks) MFMA-B-fragment order (bf16).
// Wpack[i]: e=i&7, l=(i>>3)&63, ks=(i>>9)&7, gate=(i>>12)&3, w=(i>>14)&3, cb=i>>16
//   -> Whh[gate*1024 + cb*16 + (l&15)][w*256 + ks*32 + (l>>4)*8 + e]
// ---------------------------------------------------------------------------
__global__ __launch_bounds__(256) void prep_kernel(
    const float* __restrict__ Whh, const float* __restrict__ bih,
    const float* __restrict__ bhh, const float* __restrict__ h0,
    unsigned short* __restrict__ Wpack, float* __restrict__ biasSum,
    unsigned short* __restrict__ hA){
  int i = blockIdx.x * 256 + threadIdx.x;
  if (i < G4) biasSum[i] = bih[i] + bhh[i];
  if (i < BATCH*HDIM) hA[i] = f2bf(h0[i]);
  if (i < G4*HDIM){
    int e = i & 7, l = (i >> 3) & 63, ks = (i >> 9) & 7;
    int gate = (i >> 12) & 3, w = (i >> 14) & 3, cb = i >> 16;
    int row = gate * HDIM + cb * 16 + (l & 15);
    int k = w * 256 + ks * 32 + (l >> 4) * 8 + e;
    Wpack[i] = f2bf(Whh[row * HDIM + k]);
  }
}

// ---------------------------------------------------------------------------
// x_gates GEMM: out[m][n] = sum_k In[m][k] * Wih[n][k] + biasSum[n]
// Writes packed xg[s][bid][gate][jl][bl]  (bid = (bglob>>4)*64 + (jglob>>4)):
// recurrence thread tid (j = tid>>4, bl = tid&15) reads gate*256 + tid.
// ---------------------------------------------------------------------------
template<typename XGT>
__global__ __launch_bounds__(256) void xg_gemm(
    const float* __restrict__ In, const float* __restrict__ Wih,
    const float* __restrict__ biasSum, XGT* __restrict__ xg){
  __shared__ __align__(16) unsigned short Abuf[128 * 72];
  __shared__ __align__(16) unsigned short Bbuf[128 * 72];
  const int bid = blockIdx.x;
  const int tm = bid >> 5, tn = bid & 31;
  const int bm0 = tm * 128, bn0 = tn * 128;
  const int tid = threadIdx.x;
  const int wid = tid >> 6, l = tid & 63;
  const int wm = wid >> 1, wn = wid & 1;
  const int lr = tid >> 4;
  const int lk = (tid & 15) * 4;

  f32x4 acc[4][4];
  #pragma unroll
  for (int a = 0; a < 4; ++a)
    #pragma unroll
    for (int b = 0; b < 4; ++b) acc[a][b] = (f32x4){0.f, 0.f, 0.f, 0.f};

  for (int kt = 0; kt < 16; ++kt){
    #pragma unroll
    for (int it = 0; it < 8; ++it){
      int r = lr + it * 16;
      f32x4 a4 = *reinterpret_cast<const f32x4*>(&In[(size_t)(bm0 + r) * IDIM + kt * 64 + lk]);
      ushort4v ab; ab[0]=f2bf(a4[0]); ab[1]=f2bf(a4[1]); ab[2]=f2bf(a4[2]); ab[3]=f2bf(a4[3]);
      *reinterpret_cast<ushort4v*>(&Abuf[r * 72 + lk]) = ab;
      f32x4 b4 = *reinterpret_cast<const f32x4*>(&Wih[(size_t)(bn0 + r) * IDIM + kt * 64 + lk]);
      ushort4v bb; bb[0]=f2bf(b4[0]); bb[1]=f2bf(b4[1]); bb[2]=f2bf(b4[2]); bb[3]=f2bf(b4[3]);
      *reinterpret_cast<ushort4v*>(&Bbuf[r * 72 + lk]) = bb;
    }
    __syncthreads();
    #pragma unroll
    for (int ks = 0; ks < 2; ++ks){
      short8 af[4], bfv[4];
      #pragma unroll
      for (int f = 0; f < 4; ++f){
        af[f]  = *reinterpret_cast<const short8*>(&Abuf[(wm*64 + f*16 + (l & 15)) * 72 + ks*32 + (l >> 4) * 8]);
        bfv[f] = *reinterpret_cast<const short8*>(&Bbuf[(wn*64 + f*16 + (l & 15)) * 72 + ks*32 + (l >> 4) * 8]);
      }
      #pragma unroll
      for (int fm = 0; fm < 4; ++fm)
        #pragma unroll
        for (int fn = 0; fn < 4; ++fn)
          acc[fm][fn] = mfma_bf16(af[fm], bfv[fn], acc[fm][fn]);
    }
    __syncthreads();
  }

  const int q = l >> 4, c16 = l & 15;
  #pragma unroll
  for (int fn = 0; fn < 4; ++fn){
    int n = bn0 + wn * 64 + fn * 16 + c16;
    float bias = biasSum[n];
    int gate = n >> 10, jglob = n & 1023;
    int cb = jglob >> 4, jl = jglob & 15;
    #pragma unroll
    for (int fm = 0; fm < 4; ++fm){
      int m0 = bm0 + wm * 64 + fm * 16 + q * 4;
      int s = m0 >> 6, bglob = m0 & 63;
      int g = bglob >> 4, bl0 = bglob & 15;   // bl0 = q*4, rows r contiguous
      int rbid = g * 64 + cb;
      f32x4 v = acc[fm][fn];
      v[0] += bias; v[1] += bias; v[2] += bias; v[3] += bias;
      size_t base = (((size_t)s * 256 + rbid) * 4 + gate) * 256 + jl * 16 + bl0;
      xg_store(&xg[base], v);
    }
  }
}

// ---------------------------------------------------------------------------
// recurrence: 256 persistent blocks = (g: 4 batch-groups) x (cb: 64 col-blocks).
// Block (g,cb): 16 batches x 16 h-cols. Waves split K (256 each); W B-frags in
// VGPRs (128/lane); cross-wave reduce via padded LDS. h + flags via sc0sc1.
// xg prefetched one step ahead (plain loads; barrier's syncthreads drains them).
// ---------------------------------------------------------------------------
template<typename XGT>
__global__ __launch_bounds__(256, 1) void recur_kernel(
    const float* __restrict__ h0, const float* __restrict__ c0,
    const float* __restrict__ ret, const unsigned short* __restrict__ Wpack,
    const XGT* __restrict__ xg, unsigned short* __restrict__ hA,
    unsigned short* __restrict__ hB, float* __restrict__ out,
    float* __restrict__ hc_out, unsigned* __restrict__ flags){
  __shared__ float part[16 * 272 + 16];   // [w*4+gate][m]*17+[n], pad stride 17

  const int bid = blockIdx.x;
  const int cb = bid & 63, g = bid >> 6;
  const int tid = threadIdx.x;
  const int w = tid >> 6, l = tid & 63;
  const int lm = l & 15, lq = l >> 4;

  // W fragments for this (cb, wave): 4 gates x 8 ks, 128 VGPRs/lane
  short8 Wf[4][8];
  {
    const short8* wp = reinterpret_cast<const short8*>(Wpack)
                     + (size_t)(cb * 4 + w) * 2048 + l;
    #pragma unroll
    for (int gate = 0; gate < 4; ++gate)
      #pragma unroll
      for (int ks = 0; ks < 8; ++ks)
        Wf[gate][ks] = wp[(gate * 8 + ks) * 64];
  }

  const int bl = tid & 15, j = tid >> 4;          // batch-in-group, col-in-block
  const int bglob = g * 16 + bl, jglob = cb * 16 + j;
  float c_reg = c0[bglob * HDIM + jglob];
  float h_reg = h0[bglob * HDIM + jglob];
  float r_reg = ret[jglob];

  // preload xg for s=0
  XGT xraw[4];
  {
    const XGT* xp0 = xg + (size_t)bid * 1024 + tid;
    #pragma unroll
    for (int gate = 0; gate < 4; ++gate) xraw[gate] = xp0[gate * 256];
  }

  for (int s = 0; s < S_LEN; ++s){
    const unsigned short* cur = (s & 1) ? hB : hA;
    unsigned short* nxt = (s & 1) ? hA : hB;

    // h fragment: row g*16+lm, k = w*256 + lq*8 (+ks*32 via asm offsets)
    const unsigned short* hp = cur + (size_t)(g * 16 + lm) * HDIM + w * 256 + lq * 8;
    short8 hr[8];
    load8_bypass(hp, hr);                 // complete on return (internal vmcnt0)

    f32x4 acc[4];
    #pragma unroll
    for (int gate = 0; gate < 4; ++gate) acc[gate] = (f32x4){0.f, 0.f, 0.f, 0.f};
    #pragma unroll
    for (int ks = 0; ks < 8; ++ks){
      acc[0] = mfma_bf16(hr[ks], Wf[0][ks], acc[0]);
      acc[1] = mfma_bf16(hr[ks], Wf[1][ks], acc[1]);
      acc[2] = mfma_bf16(hr[ks], Wf[2][ks], acc[2]);
      acc[3] = mfma_bf16(hr[ks], Wf[3][ks], acc[3]);
    }

    // partials to LDS: D layout col=lane&15, row=(lane>>4)*4+r
    #pragma unroll
    for (int gate = 0; gate < 4; ++gate)
      #pragma unroll
      for (int r = 0; r < 4; ++r)
        part[(w * 4 + gate) * 272 + (lq * 4 + r) * 17 + lm] = acc[gate][r];
    __syncthreads();

    // prefetch next step's xg (plain loads; drained by barrier's syncthreads)
    const int sn = (s + 1 < S_LEN) ? s + 1 : s;
    const XGT* xpn = xg + ((size_t)sn * 256 + bid) * 1024 + tid;
    XGT xnext[4];
    #pragma unroll
    for (int gate = 0; gate < 4; ++gate) xnext[gate] = xpn[gate * 256];

    // reduce + gate math; c,h in registers of thread (bl,j)
    float gv[4];
    #pragma unroll
    for (int gate = 0; gate < 4; ++gate){
      float sum = tofloat(xraw[gate]);
      #pragma unroll
      for (int ww = 0; ww < 4; ++ww)
        sum += part[(ww * 4 + gate) * 272 + bl * 17 + j];
      gv[gate] = sum;
    }
    float ig = sigf(gv[0]), fg = sigf(gv[1]);
    float gt = tanhf_fast(gv[2]), og = sigf(gv[3]);
    float cy = fg * c_reg + ig * gt;
    float hy = og * tanhf_fast(cy);
    hy = r_reg * h_reg + (1.0f - r_reg) * hy;
    c_reg = cy; h_reg = hy;
    store_short_bypass(&nxt[bglob * HDIM + jglob], (unsigned)f2bf(hy));
    out[((size_t)s * BATCH + bglob) * HDIM + jglob] = hy;

    // ---- grid barrier (round-3 proven structure) ----
    asm volatile("s_waitcnt vmcnt(0)" ::: "memory");  // own h' store at LLC
    __syncthreads();                                   // all waves drained
    const unsigned tgt = (unsigned)(s + 1);
    if (tid == 0)
      store_dword_bypass(&flags[bid], tgt);
    if (tid < 64){
      const unsigned* fp = flags + (tid << 2);
      unsigned spins = 0;
      for (;;){
        uint4v f = load4_flags_bypass(fp);
        if (f[0] >= tgt && f[1] >= tgt && f[2] >= tgt && f[3] >= tgt) break;
        if (++spins > 50000000u) break;   // safety bailout, never expected
      }
    }
    __syncthreads();   // also drains vmcnt: xnext guaranteed resident after this

    #pragma unroll
    for (int gate = 0; gate < 4; ++gate) xraw[gate] = xnext[gate];
  }

  hc_out[bglob * HDIM + jglob] = h_reg;
  hc_out[BATCH * HDIM + bglob * HDIM + jglob] = c_reg;
}

// ---------------------------------------------------------------------------
extern "C" void kernel_launch(void* const* d_in, const int* in_sizes, int n_in,
                              void* d_out, int out_size, void* d_ws, size_t ws_size,
                              hipStream_t stream){
  const float* In  = (const float*)d_in[0];
  const float* h0  = (const float*)d_in[1];
  const float* c0  = (const float*)d_in[2];
  const float* Wih = (const float*)d_in[3];
  const float* Whh = (const float*)d_in[4];
  const float* bih = (const float*)d_in[5];
  const float* bhh = (const float*)d_in[6];
  const float* ret = (const float*)d_in[7];
  float* out = (float*)d_out;

  char* ws = (char*)d_ws;
  const size_t off_flags = 0;                         // 1 KB (256 u32)
  const size_t off_bias  = 1024;
  const size_t off_hA    = 17408;
  const size_t off_hB    = off_hA + 131072;
  const size_t off_wp    = off_hB + 131072;
  const size_t off_xg    = off_wp + 8388608;
  const size_t xg_elems  = (size_t)S_LEN * G4 * BATCH;
  const size_t need_f32  = off_xg + xg_elems * 4;
  const size_t need_b16  = off_xg + xg_elems * 2;

  unsigned*       flags   = (unsigned*)(ws + off_flags);
  float*          biasSum = (float*)(ws + off_bias);
  unsigned short* hA      = (unsigned short*)(ws + off_hA);
  unsigned short* hB      = (unsigned short*)(ws + off_hB);
  unsigned short* Wpack   = (unsigned short*)(ws + off_wp);

  if (ws_size < need_b16) return;  // cannot run; fail validation loudly

  (void)hipMemsetAsync(ws + off_flags, 0, 1024, stream);
  prep_kernel<<<16384, 256, 0, stream>>>(Whh, bih, bhh, h0, Wpack, biasSum, hA);

  float* hc_out = out + (size_t)S_LEN * BATCH * HDIM;
  if (ws_size >= need_f32){
    float* xg = (float*)(ws + off_xg);
    xg_gemm<float><<<8192, 256, 0, stream>>>(In, Wih, biasSum, xg);
    recur_kernel<float><<<NBLK, 256, 0, stream>>>(h0, c0, ret, Wpack, xg, hA, hB,
                                                  out, hc_out, flags);
  } else {
    unsigned short* xg = (unsigned short*)(ws + off_xg);
    xg_gemm<unsigned short><<<8192, 256, 0, stream>>>(In, Wih, biasSum, xg);
    recur_kernel<unsigned short><<<NBLK, 256, 0, stream>>>(h0, c0, ret, Wpack, xg,
                                                           hA, hB, out, hc_out, flags);
  }
}

// Round 6
// 3687.207 us; speedup vs baseline: 5.1306x; 1.0274x over previous
//
#include <hip/hip_runtime.h>
#include <hip/hip_bf16.h>
#include <cstdint>

#define S_LEN 512
#define BATCH 64
#define IDIM  1024
#define HDIM  1024
#define G4    4096
#define NBLK  256   // recurrence grid: 4 batch-groups x 64 col-blocks

typedef __attribute__((ext_vector_type(8))) short short8;
typedef __attribute__((ext_vector_type(4))) float f32x4;
typedef __attribute__((ext_vector_type(4))) unsigned short ushort4v;
typedef __attribute__((ext_vector_type(4))) unsigned int uint4v;

__device__ __forceinline__ unsigned short f2bf(float f){
  union { float f; unsigned u; } v; v.f = f;
  unsigned r = (v.u + 0x7fffu + ((v.u >> 16) & 1u)) >> 16;
  return (unsigned short)r;
}
__device__ __forceinline__ float bf2f(unsigned short s){
  union { unsigned u; float f; } v; v.u = ((unsigned)s) << 16;
  return v.f;
}
__device__ __forceinline__ float sigf(float x){ return 1.0f / (1.0f + __expf(-x)); }
__device__ __forceinline__ float tanhf_fast(float x){
  float e = __expf(2.0f * x);
  return 1.0f - 2.0f / (e + 1.0f);
}
__device__ __forceinline__ f32x4 mfma_bf16(short8 a, short8 b, f32x4 c){
  return __builtin_amdgcn_mfma_f32_16x16x32_bf16(a, b, c, 0, 0, 0);
}
__device__ __forceinline__ float tofloat(float v){ return v; }
__device__ __forceinline__ float tofloat(unsigned short v){ return bf2f(v); }

// ---- LLC-coherent (L2-bypassing) helpers for cross-block data ----
// Self-contained: internal vmcnt(0) (round-4 lesson: no cross-asm counting).
__device__ __forceinline__ void load8_bypass(const unsigned short* p, short8* d){
  asm volatile(
    "global_load_dwordx4 %0, %8, off sc0 sc1\n\t"
    "global_load_dwordx4 %1, %8, off offset:64 sc0 sc1\n\t"
    "global_load_dwordx4 %2, %8, off offset:128 sc0 sc1\n\t"
    "global_load_dwordx4 %3, %8, off offset:192 sc0 sc1\n\t"
    "global_load_dwordx4 %4, %8, off offset:256 sc0 sc1\n\t"
    "global_load_dwordx4 %5, %8, off offset:320 sc0 sc1\n\t"
    "global_load_dwordx4 %6, %8, off offset:384 sc0 sc1\n\t"
    "global_load_dwordx4 %7, %8, off offset:448 sc0 sc1\n\t"
    "s_waitcnt vmcnt(0)"
    : "=&v"(d[0]), "=&v"(d[1]), "=&v"(d[2]), "=&v"(d[3]),
      "=&v"(d[4]), "=&v"(d[5]), "=&v"(d[6]), "=&v"(d[7])
    : "v"(p)
    : "memory");
}
__device__ __forceinline__ void store_short_bypass(unsigned short* p, unsigned v){
  asm volatile("global_store_short %0, %1, off sc0 sc1" :: "v"(p), "v"(v) : "memory");
}
__device__ __forceinline__ void store_dword_bypass(unsigned* p, unsigned v){
  asm volatile("global_store_dword %0, %1, off sc0 sc1" :: "v"(p), "v"(v) : "memory");
}
__device__ __forceinline__ uint4v load4_flags_bypass(const unsigned* p){
  uint4v f;
  asm volatile("global_load_dwordx4 %0, %1, off sc0 sc1\n\ts_waitcnt vmcnt(0)"
               : "=&v"(f) : "v"(p) : "memory");
  return f;
}

// xg scalar store helpers (f32 or bf16 storage)
__device__ __forceinline__ void xg_store1(float* p, float v){ *p = v; }
__device__ __forceinline__ void xg_store1(unsigned short* p, float v){ *p = f2bf(v); }

// ---------------------------------------------------------------------------
// prep: pack W_hh into per-(cb,wave,gate,ks) MFMA-B-fragment order (bf16).
// Wpack[i]: e=i&7, l=(i>>3)&63, ks=(i>>9)&7, gate=(i>>12)&3, w=(i>>14)&3, cb=i>>16
//   -> Whh[gate*1024 + cb*16 + (l&15)][w*256 + ks*32 + (l>>4)*8 + e]
// ---------------------------------------------------------------------------
__global__ __launch_bounds__(256) void prep_kernel(
    const float* __restrict__ Whh, const float* __restrict__ bih,
    const float* __restrict__ bhh, const float* __restrict__ h0,
    unsigned short* __restrict__ Wpack, float* __restrict__ biasSum,
    unsigned short* __restrict__ hA){
  int i = blockIdx.x * 256 + threadIdx.x;
  if (i < G4) biasSum[i] = bih[i] + bhh[i];
  if (i < BATCH*HDIM) hA[i] = f2bf(h0[i]);
  if (i < G4*HDIM){
    int e = i & 7, l = (i >> 3) & 63, ks = (i >> 9) & 7;
    int gate = (i >> 12) & 3, w = (i >> 14) & 3, cb = i >> 16;
    int row = gate * HDIM + cb * 16 + (l & 15);
    int k = w * 256 + ks * 32 + (l >> 4) * 8 + e;
    Wpack[i] = f2bf(Whh[row * HDIM + k]);
  }
}

// ---------------------------------------------------------------------------
// x_gates GEMM: out[m][n] = sum_k In[m][k] * Wih[n][k] + biasSum[n]
// Packed xg[s][rbid][gate][bl][jl] (rbid = (bglob>>4)*64 + (jglob>>4)):
// recurrence thread tid (bl = tid>>4, j = tid&15) reads gate*256 + tid.
// ---------------------------------------------------------------------------
template<typename XGT>
__global__ __launch_bounds__(256) void xg_gemm(
    const float* __restrict__ In, const float* __restrict__ Wih,
    const float* __restrict__ biasSum, XGT* __restrict__ xg){
  __shared__ __align__(16) unsigned short Abuf[128 * 72];
  __shared__ __align__(16) unsigned short Bbuf[128 * 72];
  const int bid = blockIdx.x;
  const int tm = bid >> 5, tn = bid & 31;
  const int bm0 = tm * 128, bn0 = tn * 128;
  const int tid = threadIdx.x;
  const int wid = tid >> 6, l = tid & 63;
  const int wm = wid >> 1, wn = wid & 1;
  const int lr = tid >> 4;
  const int lk = (tid & 15) * 4;

  f32x4 acc[4][4];
  #pragma unroll
  for (int a = 0; a < 4; ++a)
    #pragma unroll
    for (int b = 0; b < 4; ++b) acc[a][b] = (f32x4){0.f, 0.f, 0.f, 0.f};

  for (int kt = 0; kt < 16; ++kt){
    #pragma unroll
    for (int it = 0; it < 8; ++it){
      int r = lr + it * 16;
      f32x4 a4 = *reinterpret_cast<const f32x4*>(&In[(size_t)(bm0 + r) * IDIM + kt * 64 + lk]);
      ushort4v ab; ab[0]=f2bf(a4[0]); ab[1]=f2bf(a4[1]); ab[2]=f2bf(a4[2]); ab[3]=f2bf(a4[3]);
      *reinterpret_cast<ushort4v*>(&Abuf[r * 72 + lk]) = ab;
      f32x4 b4 = *reinterpret_cast<const f32x4*>(&Wih[(size_t)(bn0 + r) * IDIM + kt * 64 + lk]);
      ushort4v bb; bb[0]=f2bf(b4[0]); bb[1]=f2bf(b4[1]); bb[2]=f2bf(b4[2]); bb[3]=f2bf(b4[3]);
      *reinterpret_cast<ushort4v*>(&Bbuf[r * 72 + lk]) = bb;
    }
    __syncthreads();
    #pragma unroll
    for (int ks = 0; ks < 2; ++ks){
      short8 af[4], bfv[4];
      #pragma unroll
      for (int f = 0; f < 4; ++f){
        af[f]  = *reinterpret_cast<const short8*>(&Abuf[(wm*64 + f*16 + (l & 15)) * 72 + ks*32 + (l >> 4) * 8]);
        bfv[f] = *reinterpret_cast<const short8*>(&Bbuf[(wn*64 + f*16 + (l & 15)) * 72 + ks*32 + (l >> 4) * 8]);
      }
      #pragma unroll
      for (int fm = 0; fm < 4; ++fm)
        #pragma unroll
        for (int fn = 0; fn < 4; ++fn)
          acc[fm][fn] = mfma_bf16(af[fm], bfv[fn], acc[fm][fn]);
    }
    __syncthreads();
  }

  const int q = l >> 4, c16 = l & 15;
  #pragma unroll
  for (int fn = 0; fn < 4; ++fn){
    int n = bn0 + wn * 64 + fn * 16 + c16;
    float bias = biasSum[n];
    int gate = n >> 10, jglob = n & 1023;
    int cb = jglob >> 4, jl = jglob & 15;
    #pragma unroll
    for (int fm = 0; fm < 4; ++fm){
      int m0 = bm0 + wm * 64 + fm * 16 + q * 4;
      int s = m0 >> 6, bglob = m0 & 63;
      int g = bglob >> 4, bl0 = bglob & 15;
      int rbid = g * 64 + cb;
      size_t base = (((size_t)s * 256 + rbid) * 4 + gate) * 256;
      f32x4 v = acc[fm][fn];
      #pragma unroll
      for (int r = 0; r < 4; ++r)
        xg_store1(&xg[base + (bl0 + r) * 16 + jl], v[r] + bias);
    }
  }
}

// ---------------------------------------------------------------------------
// recurrence: 256 persistent blocks = (g: 4 batch-groups) x (cb: 64 col-blocks).
// PER-GROUP barrier (64 blocks, per-wave flags). Waves split K (256 each);
// W B-frags in VGPRs; h + flags via sc0sc1 (LLC-coherent).
// Critical path per step: h-load -> MFMA/reduce -> h'store -> drain -> flag
// -> poll. xg prefetch + out[] store are OFF the pre-flag path.
// ---------------------------------------------------------------------------
template<typename XGT>
__global__ __launch_bounds__(256, 1) void recur_kernel(
    const float* __restrict__ h0, const float* __restrict__ c0,
    const float* __restrict__ ret, const unsigned short* __restrict__ Wpack,
    const XGT* __restrict__ xg, unsigned short* __restrict__ hA,
    unsigned short* __restrict__ hB, float* __restrict__ out,
    float* __restrict__ hc_out, unsigned* __restrict__ flags){
  __shared__ float part[16 * 272];   // [w*4+gate]*272 + m*17 + n

  const int bid = blockIdx.x;
  const int cb = bid & 63, g = bid >> 6;
  const int tid = threadIdx.x;
  const int w = tid >> 6, l = tid & 63;
  const int lm = l & 15, lq = l >> 4;

  // W fragments for this (cb, wave): 4 gates x 8 ks, 128 VGPRs/lane
  short8 Wf[4][8];
  {
    const short8* wp = reinterpret_cast<const short8*>(Wpack)
                     + (size_t)(cb * 4 + w) * 2048 + l;
    #pragma unroll
    for (int gate = 0; gate < 4; ++gate)
      #pragma unroll
      for (int ks = 0; ks < 8; ++ks)
        Wf[gate][ks] = wp[(gate * 8 + ks) * 64];
  }

  const int bl = tid >> 4, j = tid & 15;   // batch-in-group, col-in-block
  const int bglob = g * 16 + bl, jglob = cb * 16 + j;
  float c_reg = c0[bglob * HDIM + jglob];
  float h_reg = h0[bglob * HDIM + jglob];
  float r_reg = ret[jglob];

  unsigned* gflags = flags + g * 256;      // this group's 256 per-wave flags

  // preload xg for s=0
  XGT xraw[4];
  {
    const XGT* xp0 = xg + (size_t)bid * 1024 + tid;
    #pragma unroll
    for (int gate = 0; gate < 4; ++gate) xraw[gate] = xp0[gate * 256];
  }

  for (int s = 0; s < S_LEN; ++s){
    const unsigned short* cur = (s & 1) ? hB : hA;
    unsigned short* nxt = (s & 1) ? hA : hB;

    // h fragment: row g*16+lm, k = w*256 + lq*8 (+ks*32 via asm offsets)
    const unsigned short* hp = cur + (size_t)(g * 16 + lm) * HDIM + w * 256 + lq * 8;
    short8 hr[8];
    load8_bypass(hp, hr);                 // complete on return (internal vmcnt0)

    // prefetch next step's xg NOW: latency retires under MFMA/reduce;
    // sync#1's vmcnt drain guarantees completion before use.
    const int sn = (s + 1 < S_LEN) ? s + 1 : s;
    const XGT* xpn = xg + ((size_t)sn * 256 + bid) * 1024 + tid;
    XGT xnext[4];
    #pragma unroll
    for (int gate = 0; gate < 4; ++gate) xnext[gate] = xpn[gate * 256];

    f32x4 acc[4];
    #pragma unroll
    for (int gate = 0; gate < 4; ++gate) acc[gate] = (f32x4){0.f, 0.f, 0.f, 0.f};
    #pragma unroll
    for (int ks = 0; ks < 8; ++ks){
      acc[0] = mfma_bf16(hr[ks], Wf[0][ks], acc[0]);
      acc[1] = mfma_bf16(hr[ks], Wf[1][ks], acc[1]);
      acc[2] = mfma_bf16(hr[ks], Wf[2][ks], acc[2]);
      acc[3] = mfma_bf16(hr[ks], Wf[3][ks], acc[3]);
    }

    // partials to LDS: D layout col=lane&15, row=(lane>>4)*4+r
    #pragma unroll
    for (int gate = 0; gate < 4; ++gate)
      #pragma unroll
      for (int r = 0; r < 4; ++r)
        part[(w * 4 + gate) * 272 + (lq * 4 + r) * 17 + lm] = acc[gate][r];
    __syncthreads();   // sync#1 (also drains xnext prefetch)

    // reduce + gate math; c,h in registers of thread (bl,j)
    float gv[4];
    #pragma unroll
    for (int gate = 0; gate < 4; ++gate){
      float sum = tofloat(xraw[gate]);
      #pragma unroll
      for (int ww = 0; ww < 4; ++ww)
        sum += part[(ww * 4 + gate) * 272 + bl * 17 + j];
      gv[gate] = sum;
    }
    float ig = sigf(gv[0]), fg = sigf(gv[1]);
    float gt = tanhf_fast(gv[2]), og = sigf(gv[3]);
    float cy = fg * c_reg + ig * gt;
    float hy = og * tanhf_fast(cy);
    hy = r_reg * h_reg + (1.0f - r_reg) * hy;
    c_reg = cy; h_reg = hy;
    // coalesced h' store: 16 consecutive lanes -> 16 consecutive shorts (32B)
    store_short_bypass(&nxt[bglob * HDIM + jglob], (unsigned)f2bf(hy));

    // ---- per-group barrier: per-wave drain + per-wave flag, wave 0 polls ----
    asm volatile("s_waitcnt vmcnt(0)" ::: "memory");  // own wave's h' at LLC
    const unsigned tgt = (unsigned)(s + 1);
    if (l == 0)
      store_dword_bypass(&gflags[cb * 4 + w], tgt);   // wave arrival
    if (w == 0){                        // wave 0: lane l polls flags[4l..4l+3]
      const unsigned* fp = gflags + (l << 2);
      unsigned spins = 0;
      for (;;){
        uint4v f = load4_flags_bypass(fp);
        if (f[0] >= tgt && f[1] >= tgt && f[2] >= tgt && f[3] >= tgt) break;
        if (++spins > 50000000u) break;   // safety bailout, never expected
      }
    }
    __syncthreads();   // sync#2: all waves see the barrier passed

    // out[] store AFTER the barrier: retires under next step's h-load
    out[((size_t)s * BATCH + bglob) * HDIM + jglob] = h_reg;

    #pragma unroll
    for (int gate = 0; gate < 4; ++gate) xraw[gate] = xnext[gate];
  }

  hc_out[bglob * HDIM + jglob] = h_reg;
  hc_out[BATCH * HDIM + bglob * HDIM + jglob] = c_reg;
}

// ---------------------------------------------------------------------------
extern "C" void kernel_launch(void* const* d_in, const int* in_sizes, int n_in,
                              void* d_out, int out_size, void* d_ws, size_t ws_size,
                              hipStream_t stream){
  const float* In  = (const float*)d_in[0];
  const float* h0  = (const float*)d_in[1];
  const float* c0  = (const float*)d_in[2];
  const float* Wih = (const float*)d_in[3];
  const float* Whh = (const float*)d_in[4];
  const float* bih = (const float*)d_in[5];
  const float* bhh = (const float*)d_in[6];
  const float* ret = (const float*)d_in[7];
  float* out = (float*)d_out;

  char* ws = (char*)d_ws;
  const size_t off_flags = 0;                          // 4 KB (4 groups x 256)
  const size_t off_bias  = 4096;
  const size_t off_hA    = 4096 + 16384;               // 20480
  const size_t off_hB    = off_hA + 131072;
  const size_t off_wp    = off_hB + 131072;
  const size_t off_xg    = off_wp + 8388608;
  const size_t xg_elems  = (size_t)S_LEN * G4 * BATCH;
  const size_t need_f32  = off_xg + xg_elems * 4;
  const size_t need_b16  = off_xg + xg_elems * 2;

  unsigned*       flags   = (unsigned*)(ws + off_flags);
  float*          biasSum = (float*)(ws + off_bias);
  unsigned short* hA      = (unsigned short*)(ws + off_hA);
  unsigned short* hB      = (unsigned short*)(ws + off_hB);
  unsigned short* Wpack   = (unsigned short*)(ws + off_wp);

  if (ws_size < need_b16) return;  // cannot run; fail validation loudly

  (void)hipMemsetAsync(ws + off_flags, 0, 4096, stream);
  prep_kernel<<<16384, 256, 0, stream>>>(Whh, bih, bhh, h0, Wpack, biasSum, hA);

  float* hc_out = out + (size_t)S_LEN * BATCH * HDIM;
  if (ws_size >= need_f32){
    float* xg = (float*)(ws + off_xg);
    xg_gemm<float><<<8192, 256, 0, stream>>>(In, Wih, biasSum, xg);
    recur_kernel<float><<<NBLK, 256, 0, stream>>>(h0, c0, ret, Wpack, xg, hA, hB,
                                                  out, hc_out, flags);
  } else {
    unsigned short* xg = (unsigned short*)(ws + off_xg);
    xg_gemm<unsigned short><<<8192, 256, 0, stream>>>(In, Wih, biasSum, xg);
    recur_kernel<unsigned short><<<NBLK, 256, 0, stream>>>(h0, c0, ret, Wpack, xg,
                                                           hA, hB, out, hc_out, flags);
  }
}

// Round 7
// 2821.338 us; speedup vs baseline: 6.7052x; 1.3069x over previous
//
#include <hip/hip_runtime.h>
#include <hip/hip_bf16.h>
#include <cstdint>

#define S_LEN 512
#define BATCH 64
#define IDIM  1024
#define HDIM  1024
#define G4    4096
#define NBLK  256   // recurrence grid: 4 batch-groups x 64 col-blocks

typedef __attribute__((ext_vector_type(8))) short short8;
typedef __attribute__((ext_vector_type(4))) float f32x4;
typedef __attribute__((ext_vector_type(4))) unsigned short ushort4v;
typedef __attribute__((ext_vector_type(4))) unsigned int uint4v;

__device__ __forceinline__ unsigned short f2bf(float f){
  union { float f; unsigned u; } v; v.f = f;
  unsigned r = (v.u + 0x7fffu + ((v.u >> 16) & 1u)) >> 16;
  return (unsigned short)r;
}
__device__ __forceinline__ float bf2f(unsigned short s){
  union { unsigned u; float f; } v; v.u = ((unsigned)s) << 16;
  return v.f;
}
__device__ __forceinline__ float sigf(float x){ return 1.0f / (1.0f + __expf(-x)); }
__device__ __forceinline__ float tanhf_fast(float x){
  float e = __expf(2.0f * x);
  return 1.0f - 2.0f / (e + 1.0f);
}
__device__ __forceinline__ f32x4 mfma_bf16(short8 a, short8 b, f32x4 c){
  return __builtin_amdgcn_mfma_f32_16x16x32_bf16(a, b, c, 0, 0, 0);
}

// ---- LLC-coherent (L2-bypassing) helpers for cross-block data ----
// Self-contained asm blocks with INTERNAL vmcnt(0) only (round-4 lesson).

// Combined per-step load: 4 xg loads (normal cached path, HBM — issued FIRST,
// longest latency) + 8 h loads (sc0sc1, LLC-coherent). One internal vmcnt(0):
// xg HBM latency retires concurrently with the h LLC wait (max, not sum).
__device__ __forceinline__ void load_step(const float* xp, const unsigned short* hp,
                                          float* xv, short8* hr){
  asm volatile(
    "global_load_dword %0, %12, off\n\t"
    "global_load_dword %1, %12, off offset:1024\n\t"
    "global_load_dword %2, %12, off offset:2048\n\t"
    "global_load_dword %3, %12, off offset:3072\n\t"
    "global_load_dwordx4 %4, %13, off sc0 sc1\n\t"
    "global_load_dwordx4 %5, %13, off offset:64 sc0 sc1\n\t"
    "global_load_dwordx4 %6, %13, off offset:128 sc0 sc1\n\t"
    "global_load_dwordx4 %7, %13, off offset:192 sc0 sc1\n\t"
    "global_load_dwordx4 %8, %13, off offset:256 sc0 sc1\n\t"
    "global_load_dwordx4 %9, %13, off offset:320 sc0 sc1\n\t"
    "global_load_dwordx4 %10, %13, off offset:384 sc0 sc1\n\t"
    "global_load_dwordx4 %11, %13, off offset:448 sc0 sc1\n\t"
    "s_waitcnt vmcnt(0)"
    : "=&v"(xv[0]), "=&v"(xv[1]), "=&v"(xv[2]), "=&v"(xv[3]),
      "=&v"(hr[0]), "=&v"(hr[1]), "=&v"(hr[2]), "=&v"(hr[3]),
      "=&v"(hr[4]), "=&v"(hr[5]), "=&v"(hr[6]), "=&v"(hr[7])
    : "v"(xp), "v"(hp)
    : "memory");
}
__device__ __forceinline__ void load_step(const unsigned short* xp, const unsigned short* hp,
                                          float* xv, short8* hr){
  unsigned u0, u1, u2, u3;
  asm volatile(
    "global_load_ushort %0, %12, off\n\t"
    "global_load_ushort %1, %12, off offset:512\n\t"
    "global_load_ushort %2, %12, off offset:1024\n\t"
    "global_load_ushort %3, %12, off offset:1536\n\t"
    "global_load_dwordx4 %4, %13, off sc0 sc1\n\t"
    "global_load_dwordx4 %5, %13, off offset:64 sc0 sc1\n\t"
    "global_load_dwordx4 %6, %13, off offset:128 sc0 sc1\n\t"
    "global_load_dwordx4 %7, %13, off offset:192 sc0 sc1\n\t"
    "global_load_dwordx4 %8, %13, off offset:256 sc0 sc1\n\t"
    "global_load_dwordx4 %9, %13, off offset:320 sc0 sc1\n\t"
    "global_load_dwordx4 %10, %13, off offset:384 sc0 sc1\n\t"
    "global_load_dwordx4 %11, %13, off offset:448 sc0 sc1\n\t"
    "s_waitcnt vmcnt(0)"
    : "=&v"(u0), "=&v"(u1), "=&v"(u2), "=&v"(u3),
      "=&v"(hr[0]), "=&v"(hr[1]), "=&v"(hr[2]), "=&v"(hr[3]),
      "=&v"(hr[4]), "=&v"(hr[5]), "=&v"(hr[6]), "=&v"(hr[7])
    : "v"(xp), "v"(hp)
    : "memory");
  xv[0] = bf2f((unsigned short)u0); xv[1] = bf2f((unsigned short)u1);
  xv[2] = bf2f((unsigned short)u2); xv[3] = bf2f((unsigned short)u3);
}
__device__ __forceinline__ void store_short_bypass(unsigned short* p, unsigned v){
  asm volatile("global_store_short %0, %1, off sc0 sc1" :: "v"(p), "v"(v) : "memory");
}
__device__ __forceinline__ void store_dword_bypass(unsigned* p, unsigned v){
  asm volatile("global_store_dword %0, %1, off sc0 sc1" :: "v"(p), "v"(v) : "memory");
}
__device__ __forceinline__ uint4v load4_flags_bypass(const unsigned* p){
  uint4v f;
  asm volatile("global_load_dwordx4 %0, %1, off sc0 sc1\n\ts_waitcnt vmcnt(0)"
               : "=&v"(f) : "v"(p) : "memory");
  return f;
}

// xg scalar store helpers (f32 or bf16 storage)
__device__ __forceinline__ void xg_store1(float* p, float v){ *p = v; }
__device__ __forceinline__ void xg_store1(unsigned short* p, float v){ *p = f2bf(v); }

// ---------------------------------------------------------------------------
// prep: pack W_hh into per-(cb,wave,gate,ks) MFMA-B-fragment order (bf16).
// ---------------------------------------------------------------------------
__global__ __launch_bounds__(256) void prep_kernel(
    const float* __restrict__ Whh, const float* __restrict__ bih,
    const float* __restrict__ bhh, const float* __restrict__ h0,
    unsigned short* __restrict__ Wpack, float* __restrict__ biasSum,
    unsigned short* __restrict__ hA){
  int i = blockIdx.x * 256 + threadIdx.x;
  if (i < G4) biasSum[i] = bih[i] + bhh[i];
  if (i < BATCH*HDIM) hA[i] = f2bf(h0[i]);
  if (i < G4*HDIM){
    int e = i & 7, l = (i >> 3) & 63, ks = (i >> 9) & 7;
    int gate = (i >> 12) & 3, w = (i >> 14) & 3, cb = i >> 16;
    int row = gate * HDIM + cb * 16 + (l & 15);
    int k = w * 256 + ks * 32 + (l >> 4) * 8 + e;
    Wpack[i] = f2bf(Whh[row * HDIM + k]);
  }
}

// ---------------------------------------------------------------------------
// x_gates GEMM: out[m][n] = sum_k In[m][k] * Wih[n][k] + biasSum[n]
// Packed xg[s][rbid][gate][bl][jl] (rbid = (bglob>>4)*64 + (jglob>>4)):
// recurrence thread tid (bl = tid>>4, j = tid&15) reads gate*256 + tid.
// ---------------------------------------------------------------------------
template<typename XGT>
__global__ __launch_bounds__(256) void xg_gemm(
    const float* __restrict__ In, const float* __restrict__ Wih,
    const float* __restrict__ biasSum, XGT* __restrict__ xg){
  __shared__ __align__(16) unsigned short Abuf[128 * 72];
  __shared__ __align__(16) unsigned short Bbuf[128 * 72];
  const int bid = blockIdx.x;
  const int tm = bid >> 5, tn = bid & 31;
  const int bm0 = tm * 128, bn0 = tn * 128;
  const int tid = threadIdx.x;
  const int wid = tid >> 6, l = tid & 63;
  const int wm = wid >> 1, wn = wid & 1;
  const int lr = tid >> 4;
  const int lk = (tid & 15) * 4;

  f32x4 acc[4][4];
  #pragma unroll
  for (int a = 0; a < 4; ++a)
    #pragma unroll
    for (int b = 0; b < 4; ++b) acc[a][b] = (f32x4){0.f, 0.f, 0.f, 0.f};

  for (int kt = 0; kt < 16; ++kt){
    #pragma unroll
    for (int it = 0; it < 8; ++it){
      int r = lr + it * 16;
      f32x4 a4 = *reinterpret_cast<const f32x4*>(&In[(size_t)(bm0 + r) * IDIM + kt * 64 + lk]);
      ushort4v ab; ab[0]=f2bf(a4[0]); ab[1]=f2bf(a4[1]); ab[2]=f2bf(a4[2]); ab[3]=f2bf(a4[3]);
      *reinterpret_cast<ushort4v*>(&Abuf[r * 72 + lk]) = ab;
      f32x4 b4 = *reinterpret_cast<const f32x4*>(&Wih[(size_t)(bn0 + r) * IDIM + kt * 64 + lk]);
      ushort4v bb; bb[0]=f2bf(b4[0]); bb[1]=f2bf(b4[1]); bb[2]=f2bf(b4[2]); bb[3]=f2bf(b4[3]);
      *reinterpret_cast<ushort4v*>(&Bbuf[r * 72 + lk]) = bb;
    }
    __syncthreads();
    #pragma unroll
    for (int ks = 0; ks < 2; ++ks){
      short8 af[4], bfv[4];
      #pragma unroll
      for (int f = 0; f < 4; ++f){
        af[f]  = *reinterpret_cast<const short8*>(&Abuf[(wm*64 + f*16 + (l & 15)) * 72 + ks*32 + (l >> 4) * 8]);
        bfv[f] = *reinterpret_cast<const short8*>(&Bbuf[(wn*64 + f*16 + (l & 15)) * 72 + ks*32 + (l >> 4) * 8]);
      }
      #pragma unroll
      for (int fm = 0; fm < 4; ++fm)
        #pragma unroll
        for (int fn = 0; fn < 4; ++fn)
          acc[fm][fn] = mfma_bf16(af[fm], bfv[fn], acc[fm][fn]);
    }
    __syncthreads();
  }

  const int q = l >> 4, c16 = l & 15;
  #pragma unroll
  for (int fn = 0; fn < 4; ++fn){
    int n = bn0 + wn * 64 + fn * 16 + c16;
    float bias = biasSum[n];
    int gate = n >> 10, jglob = n & 1023;
    int cb = jglob >> 4, jl = jglob & 15;
    #pragma unroll
    for (int fm = 0; fm < 4; ++fm){
      int m0 = bm0 + wm * 64 + fm * 16 + q * 4;
      int s = m0 >> 6, bglob = m0 & 63;
      int g = bglob >> 4, bl0 = bglob & 15;
      int rbid = g * 64 + cb;
      size_t base = (((size_t)s * 256 + rbid) * 4 + gate) * 256;
      f32x4 v = acc[fm][fn];
      #pragma unroll
      for (int r = 0; r < 4; ++r)
        xg_store1(&xg[base + (bl0 + r) * 16 + jl], v[r] + bias);
    }
  }
}

// ---------------------------------------------------------------------------
// recurrence: 256 persistent blocks = (g: 4 batch-groups) x (cb: 64 col-blocks).
// PER-GROUP barrier; per-wave flags PADDED one 64B line per block (poll
// contention fix); s_sleep backoff. Combined xg+h load (one vmcnt0). Waves
// split K; W B-frags in VGPRs; h + flags via sc0sc1 (LLC-coherent).
// ---------------------------------------------------------------------------
template<typename XGT>
__global__ __launch_bounds__(256, 1) void recur_kernel(
    const float* __restrict__ h0, const float* __restrict__ c0,
    const float* __restrict__ ret, const unsigned short* __restrict__ Wpack,
    const XGT* __restrict__ xg, unsigned short* __restrict__ hA,
    unsigned short* __restrict__ hB, float* __restrict__ out,
    float* __restrict__ hc_out, unsigned* __restrict__ flags){
  __shared__ float part[16 * 272];   // [w*4+gate]*272 + m*17 + n

  const int bid = blockIdx.x;
  const int cb = bid & 63, g = bid >> 6;
  const int tid = threadIdx.x;
  const int w = tid >> 6, l = tid & 63;
  const int lm = l & 15, lq = l >> 4;

  // W fragments for this (cb, wave): 4 gates x 8 ks, 128 VGPRs/lane
  short8 Wf[4][8];
  {
    const short8* wp = reinterpret_cast<const short8*>(Wpack)
                     + (size_t)(cb * 4 + w) * 2048 + l;
    #pragma unroll
    for (int gate = 0; gate < 4; ++gate)
      #pragma unroll
      for (int ks = 0; ks < 8; ++ks)
        Wf[gate][ks] = wp[(gate * 8 + ks) * 64];
  }

  const int bl = tid >> 4, j = tid & 15;   // batch-in-group, col-in-block
  const int bglob = g * 16 + bl, jglob = cb * 16 + j;
  float c_reg = c0[bglob * HDIM + jglob];
  float h_reg = h0[bglob * HDIM + jglob];
  float r_reg = ret[jglob];

  // flags: one 64B line per block: gflags[cb*16 + w] (lines never shared
  // between blocks -> 64 pollers/line, writers don't fight other lines)
  unsigned* gflags = flags + g * 1024;

  for (int s = 0; s < S_LEN; ++s){
    const unsigned short* cur = (s & 1) ? hB : hA;
    unsigned short* nxt = (s & 1) ? hA : hB;

    // combined load: xg[s] (HBM, issued first) + h (LLC), single vmcnt(0)
    const unsigned short* hp = cur + (size_t)(g * 16 + lm) * HDIM + w * 256 + lq * 8;
    const XGT* xp = xg + ((size_t)s * 256 + bid) * 1024 + tid;
    float xv[4];
    short8 hr[8];
    load_step(xp, hp, xv, hr);

    f32x4 acc[4];
    #pragma unroll
    for (int gate = 0; gate < 4; ++gate) acc[gate] = (f32x4){0.f, 0.f, 0.f, 0.f};
    #pragma unroll
    for (int ks = 0; ks < 8; ++ks){
      acc[0] = mfma_bf16(hr[ks], Wf[0][ks], acc[0]);
      acc[1] = mfma_bf16(hr[ks], Wf[1][ks], acc[1]);
      acc[2] = mfma_bf16(hr[ks], Wf[2][ks], acc[2]);
      acc[3] = mfma_bf16(hr[ks], Wf[3][ks], acc[3]);
    }

    // partials to LDS: D layout col=lane&15, row=(lane>>4)*4+r
    #pragma unroll
    for (int gate = 0; gate < 4; ++gate)
      #pragma unroll
      for (int r = 0; r < 4; ++r)
        part[(w * 4 + gate) * 272 + (lq * 4 + r) * 17 + lm] = acc[gate][r];
    __syncthreads();   // sync#1 (nothing pending in vmcnt now)

    // reduce + gate math; c,h in registers of thread (bl,j)
    float gv[4];
    #pragma unroll
    for (int gate = 0; gate < 4; ++gate){
      float sum = xv[gate];
      #pragma unroll
      for (int ww = 0; ww < 4; ++ww)
        sum += part[(ww * 4 + gate) * 272 + bl * 17 + j];
      gv[gate] = sum;
    }
    float ig = sigf(gv[0]), fg = sigf(gv[1]);
    float gt = tanhf_fast(gv[2]), og = sigf(gv[3]);
    float cy = fg * c_reg + ig * gt;
    float hy = og * tanhf_fast(cy);
    hy = r_reg * h_reg + (1.0f - r_reg) * hy;
    c_reg = cy; h_reg = hy;
    // coalesced h' store: 16 consecutive lanes -> 16 consecutive shorts (32B)
    store_short_bypass(&nxt[bglob * HDIM + jglob], (unsigned)f2bf(hy));

    // ---- per-group barrier: per-wave drain + per-wave flag, wave 0 polls ----
    asm volatile("s_waitcnt vmcnt(0)" ::: "memory");  // own wave's h' at LLC
    const unsigned tgt = (unsigned)(s + 1);
    if (l == 0)
      store_dword_bypass(&gflags[cb * 16 + w], tgt);  // wave arrival
    if (w == 0){                    // wave 0: lane l polls block l's flag line
      const unsigned* fp = gflags + (l << 4);
      unsigned spins = 0;
      for (;;){
        uint4v f = load4_flags_bypass(fp);
        if (f[0] >= tgt && f[1] >= tgt && f[2] >= tgt && f[3] >= tgt) break;
        __builtin_amdgcn_s_sleep(1);      // backoff: cut poll read pressure
        if (++spins > 50000000u) break;   // safety bailout, never expected
      }
    }
    __syncthreads();   // sync#2: all waves see the barrier passed

    // out[] store AFTER the barrier: retires under next step's loads
    out[((size_t)s * BATCH + bglob) * HDIM + jglob] = h_reg;
  }

  hc_out[bglob * HDIM + jglob] = h_reg;
  hc_out[BATCH * HDIM + bglob * HDIM + jglob] = c_reg;
}

// ---------------------------------------------------------------------------
extern "C" void kernel_launch(void* const* d_in, const int* in_sizes, int n_in,
                              void* d_out, int out_size, void* d_ws, size_t ws_size,
                              hipStream_t stream){
  const float* In  = (const float*)d_in[0];
  const float* h0  = (const float*)d_in[1];
  const float* c0  = (const float*)d_in[2];
  const float* Wih = (const float*)d_in[3];
  const float* Whh = (const float*)d_in[4];
  const float* bih = (const float*)d_in[5];
  const float* bhh = (const float*)d_in[6];
  const float* ret = (const float*)d_in[7];
  float* out = (float*)d_out;

  char* ws = (char*)d_ws;
  const size_t off_flags = 0;                          // 16 KB (4 groups x 4 KB)
  const size_t off_bias  = 16384;
  const size_t off_hA    = 16384 + 16384;              // 32768
  const size_t off_hB    = off_hA + 131072;
  const size_t off_wp    = off_hB + 131072;
  const size_t off_xg    = off_wp + 8388608;
  const size_t xg_elems  = (size_t)S_LEN * G4 * BATCH;
  const size_t need_f32  = off_xg + xg_elems * 4;
  const size_t need_b16  = off_xg + xg_elems * 2;

  unsigned*       flags   = (unsigned*)(ws + off_flags);
  float*          biasSum = (float*)(ws + off_bias);
  unsigned short* hA      = (unsigned short*)(ws + off_hA);
  unsigned short* hB      = (unsigned short*)(ws + off_hB);
  unsigned short* Wpack   = (unsigned short*)(ws + off_wp);

  if (ws_size < need_b16) return;  // cannot run; fail validation loudly

  (void)hipMemsetAsync(ws + off_flags, 0, 16384, stream);
  prep_kernel<<<16384, 256, 0, stream>>>(Whh, bih, bhh, h0, Wpack, biasSum, hA);

  float* hc_out = out + (size_t)S_LEN * BATCH * HDIM;
  if (ws_size >= need_f32){
    float* xg = (float*)(ws + off_xg);
    xg_gemm<float><<<8192, 256, 0, stream>>>(In, Wih, biasSum, xg);
    recur_kernel<float><<<NBLK, 256, 0, stream>>>(h0, c0, ret, Wpack, xg, hA, hB,
                                                  out, hc_out, flags);
  } else {
    unsigned short* xg = (unsigned short*)(ws + off_xg);
    xg_gemm<unsigned short><<<8192, 256, 0, stream>>>(In, Wih, biasSum, xg);
    recur_kernel<unsigned short><<<NBLK, 256, 0, stream>>>(h0, c0, ret, Wpack, xg,
                                                           hA, hB, out, hc_out, flags);
  }
}